// Round 12
// baseline (1112.480 us; speedup 1.0000x reference)
//
#include <hip/hip_runtime.h>

typedef _Float16 f16;
typedef __attribute__((ext_vector_type(8))) _Float16 f16x8;
typedef __attribute__((ext_vector_type(4))) float f32x4;

#define BT   131072
#define DD   512
#define TMB  64              // 2 independent 32-sample tiles per block
#define NBLK (BT / TMB)      // 2048

// swizzled LDS fp16 slot (32 rows x 512 cols = 32KB):
// byte = row*1024 + (colbyte ^ ((row&7)<<4))
__device__ __forceinline__ void stA(char* tb, int row, int colbyte, float v) {
    *(f16*)(tb + row * 1024 + (colbyte ^ ((row & 7) << 4))) = (f16)v;
}
__device__ __forceinline__ f16x8 ldA8(const char* tb, int row, int kbyte) {
    return *(const f16x8*)(tb + row * 1024 + (kbyte ^ ((row & 7) << 4)));
}
__device__ __forceinline__ float ldh(const char* tb, int row, int colbyte) {
    return (float)*(const f16*)(tb + row * 1024 + (colbyte ^ ((row & 7) << 4)));
}

__device__ __forceinline__ f16x8 cvt8(const float* q) {
    float4 u0 = *(const float4*)q;
    float4 u1 = *(const float4*)(q + 4);
    f16x8 r;
    r[0] = (f16)u0.x; r[1] = (f16)u0.y; r[2] = (f16)u0.z; r[3] = (f16)u0.w;
    r[4] = (f16)u1.x; r[5] = (f16)u1.y; r[6] = (f16)u1.z; r[7] = (f16)u1.w;
    return r;
}

// Pack 6 sections of B-fragments (each 16sk x 32nsub x 64lane f16x8):
// sections 0..2: forward W1..W3  (N=out n, K=in k):   elem W[n*DD + k+j]
// sections 3..5: backward W1..W3 transposed:          elem W[(k+j)*DD + n]
__global__ void prep_w(const float* __restrict__ W1, const float* __restrict__ W2,
                       const float* __restrict__ W3, f16* __restrict__ wp) {
    int tid = blockIdx.x * 256 + threadIdx.x;
    if (tid >= 6 * 16 * 32 * 64) return;
    int lane = tid & 63;
    int frag = tid >> 6;
    int nsub = frag & 31;
    int sk   = (frag >> 5) & 15;
    int l    = frag >> 9;          // 0..5
    int lw   = l - (l >= 3 ? 3 : 0);
    const float* W = (lw == 0) ? W1 : (lw == 1) ? W2 : W3;
    int n = nsub * 16 + (lane & 15);
    int k = sk * 32 + (lane >> 4) * 8;
    f16x8 o;
    if (l < 3) {
        const float* p = W + (size_t)n * DD + k;
        #pragma unroll
        for (int j = 0; j < 8; ++j) o[j] = (f16)p[j];
    } else {
        const float* p = W + (size_t)k * DD + n;
        #pragma unroll
        for (int j = 0; j < 8; ++j) o[j] = (f16)p[j * DD];
    }
    ((f16x8*)wp)[tid] = o;
}

#define MFMA1(A, B, C) __builtin_amdgcn_mfma_f32_16x16x32_f16(A, B, C, 0, 0, 0)

// one tile, one k-slice: 2 A-rows (M=32) x 4 B frags -> 8 MFMA
#define MFMA_TILE(ACC, SA, skc, Q0, Q1, Q2, Q3)                                \
    { f16x8 a0_ = ldA8(SA, l15,      (skc) * 64 + g16 * 16);                   \
      f16x8 a1_ = ldA8(SA, 16 + l15, (skc) * 64 + g16 * 16);                   \
      ACC[0][0]=MFMA1(a0_,Q0,ACC[0][0]); ACC[0][1]=MFMA1(a0_,Q1,ACC[0][1]);    \
      ACC[0][2]=MFMA1(a0_,Q2,ACC[0][2]); ACC[0][3]=MFMA1(a0_,Q3,ACC[0][3]);    \
      ACC[1][0]=MFMA1(a1_,Q0,ACC[1][0]); ACC[1][1]=MFMA1(a1_,Q1,ACC[1][1]);    \
      ACC[1][2]=MFMA1(a1_,Q2,ACC[1][2]); ACC[1][3]=MFMA1(a1_,Q3,ACC[1][3]); }

#define ZACC(A)                                                                \
    _Pragma("unroll") for (int m_ = 0; m_ < 2; ++m_)                           \
    _Pragma("unroll") for (int n_ = 0; n_ < 4; ++n_)                           \
        A[m_][n_] = f32x4{0.f, 0.f, 0.f, 0.f};

// shared B stream feeds BOTH tiles: 4 B loads + 4 A ds_reads + 16 MFMA per sk
#define KLOOP_P(SEC, SLOT)                                                     \
  { const f16x8* wS = (const f16x8*)wp + (size_t)(SEC) * (16*32*64)            \
                    + (size_t)(wv * 4) * 64 + lane;                            \
    _Pragma("unroll 2")                                                        \
    for (int sk = 0; sk < 16; ++sk) {                                          \
      const f16x8* p_ = wS + ((size_t)sk << 11);                               \
      f16x8 q0 = p_[0], q1 = p_[64], q2 = p_[128], q3 = p_[192];               \
      MFMA_TILE(acc0, TA0 + (SLOT)*32768, sk, q0, q1, q2, q3)                  \
      MFMA_TILE(acc1, TA1 + (SLOT)*32768, sk, q0, q1, q2, q3)                  \
    } }

#define KLOOP_FW(WPTR, SLOT)                                                   \
  { _Pragma("unroll 2")                                                        \
    for (int sk = 0; sk < 16; ++sk) {                                          \
      const float* q_ = WPTR + (size_t)(wv*64 + l15)*DD + sk*32 + g16*8;       \
      f16x8 q0 = cvt8(q_), q1 = cvt8(q_ + 16*DD);                              \
      f16x8 q2 = cvt8(q_ + 32*DD), q3 = cvt8(q_ + 48*DD);                      \
      MFMA_TILE(acc0, TA0 + (SLOT)*32768, sk, q0, q1, q2, q3)                  \
      MFMA_TILE(acc1, TA1 + (SLOT)*32768, sk, q0, q1, q2, q3)                  \
    } }

#define KLOOP_BW(WPTR, SLOT)                                                   \
  { for (int sk = 0; sk < 16; ++sk) {                                          \
      const float* q_ = WPTR + (size_t)(sk*32 + g16*8)*DD + wv*64 + l15;       \
      f16x8 t0, t1, t2, t3;                                                    \
      _Pragma("unroll")                                                        \
      for (int j = 0; j < 8; ++j) {                                            \
          t0[j] = (f16)q_[j*DD];      t1[j] = (f16)q_[j*DD + 16];              \
          t2[j] = (f16)q_[j*DD + 32]; t3[j] = (f16)q_[j*DD + 48]; }            \
      MFMA_TILE(acc0, TA0 + (SLOT)*32768, sk, t0, t1, t2, t3)                  \
      MFMA_TILE(acc1, TA1 + (SLOT)*32768, sk, t0, t1, t2, t3)                  \
    } }

template<bool PREP>
__global__ __launch_bounds__(512) void mlp_fused(
    const float* __restrict__ tx,
    const float* __restrict__ W0, const float* __restrict__ b0v,
    const float* __restrict__ W1, const float* __restrict__ b1v,
    const float* __restrict__ W2, const float* __restrict__ b2v,
    const float* __restrict__ W3, const float* __restrict__ b3v,
    const float* __restrict__ W4, const float* __restrict__ b4v,
    const f16* __restrict__ wp, float* __restrict__ out)
{
    // Two sample-tiles, two ping-pong slots each (R12 slot discipline):
    // fwd: L0->s0(h1); rd s0 wr s1(h2); rd s1 wr s0(h3); rd s0 wr s1(gz4)
    // bwd: rd s1, [ldh h3@s0] wr s0(gz3); rd s0, [sg2 regs] wr s1(gz2);
    //      rd s1, [sigma1 recompute] wr s0(gz1); FIN reads s0.
    __shared__ __align__(16) short abuf_s[4 * 32 * DD];  // 128 KB
    __shared__ float txb[TMB * 3];
    __shared__ float pbuf[2][8][32];
    char* ab  = (char*)abuf_s;
    char* TA0 = ab;              // tile0: slots +0 / +32768
    char* TA1 = ab + 65536;      // tile1: slots +0 / +32768

    const int tid  = threadIdx.x;
    const int lane = tid & 63;
    const int wv   = tid >> 6;   // 0..7, owns cols [wv*64, wv*64+64)
    const int g16  = lane >> 4;
    const int l15  = lane & 15;
    const long s0g = (long)blockIdx.x * TMB;

    if (tid < TMB * 3) txb[tid] = tx[s0g * 3 + tid];
    __syncthreads();

    // ---- layer 0: h1 = sp20(W0 x + b0) -> slot0 of each tile
    {
        int n = tid;
        float w0 = W0[n*3], w1 = W0[n*3+1], w2 = W0[n*3+2], bb = b0v[n];
        #pragma unroll 4
        for (int s = 0; s < TMB; ++s) {
            float z  = fmaf(w0, txb[s*3], fmaf(w1, txb[s*3+1], fmaf(w2, txb[s*3+2], bb)));
            float aa = fabsf(z);
            float e  = __expf(-20.f * aa);
            float d2 = 1.f + e;
            float h  = fmaxf(z, 0.f) + __logf(d2) * 0.05f;
            stA(ab + (s >> 5) * 65536, s & 31, n * 2, h);
        }
    }
    __syncthreads();

    f32x4 acc0[2][4], acc1[2][4];
    f16x8 sg2a[4], sg2b[4];   // sigma2 regs (32 f16 per tile)

    // ---- fwd0: h2 = sp20(W1 h1 + b1); capture sigma2
    ZACC(acc0) ZACC(acc1)
    if constexpr (PREP) { KLOOP_P(0, 0) } else { KLOOP_FW(W1, 0) }
    #pragma unroll
    for (int n = 0; n < 4; ++n) {
        float bias = b1v[wv*64 + n*16 + l15];
        int   cb   = (wv*64 + n*16 + l15) * 2;
        #pragma unroll
        for (int m = 0; m < 2; ++m)
            #pragma unroll
            for (int r = 0; r < 4; ++r) {
                int row = m*16 + g16*4 + r;
                int idx = m*16 + n*4 + r;
                { float z = acc0[m][n][r] + bias;
                  float e = __expf(-20.f * fabsf(z));
                  float d2 = 1.f + e;
                  float h = fmaxf(z, 0.f) + __logf(d2) * 0.05f;
                  sg2a[idx>>3][idx&7] = (f16)((z > 0.f ? 1.f : e) * __builtin_amdgcn_rcpf(d2));
                  stA(TA0 + 32768, row, cb, h); }
                { float z = acc1[m][n][r] + bias;
                  float e = __expf(-20.f * fabsf(z));
                  float d2 = 1.f + e;
                  float h = fmaxf(z, 0.f) + __logf(d2) * 0.05f;
                  sg2b[idx>>3][idx&7] = (f16)((z > 0.f ? 1.f : e) * __builtin_amdgcn_rcpf(d2));
                  stA(TA1 + 32768, row, cb, h); }
            }
    }
    __syncthreads();

    // ---- fwd1: h3 = sp20(W2 h2 + b2) -> slot0
    ZACC(acc0) ZACC(acc1)
    if constexpr (PREP) { KLOOP_P(1, 1) } else { KLOOP_FW(W2, 1) }
    #pragma unroll
    for (int n = 0; n < 4; ++n) {
        float bias = b2v[wv*64 + n*16 + l15];
        int   cb   = (wv*64 + n*16 + l15) * 2;
        #pragma unroll
        for (int m = 0; m < 2; ++m)
            #pragma unroll
            for (int r = 0; r < 4; ++r) {
                int row = m*16 + g16*4 + r;
                { float z = acc0[m][n][r] + bias;
                  float e = __expf(-20.f * fabsf(z));
                  float d2 = 1.f + e;
                  stA(TA0, row, cb, fmaxf(z, 0.f) + __logf(d2) * 0.05f); }
                { float z = acc1[m][n][r] + bias;
                  float e = __expf(-20.f * fabsf(z));
                  float d2 = 1.f + e;
                  stA(TA1, row, cb, fmaxf(z, 0.f) + __logf(d2) * 0.05f); }
            }
    }
    __syncthreads();

    // ---- fwd2: z4 = W3 h3 + b3 -> gz4 = W4[0]*sigma4 -> slot1 ; p partials
    ZACC(acc0) ZACC(acc1)
    if constexpr (PREP) { KLOOP_P(2, 0) } else { KLOOP_FW(W3, 0) }
    #pragma unroll
    for (int m = 0; m < 2; ++m)
        #pragma unroll
        for (int r = 0; r < 4; ++r) {
            int row = m*16 + g16*4 + r;
            float pp0 = 0.f, pp1 = 0.f;
            #pragma unroll
            for (int n = 0; n < 4; ++n) {
                int col = wv*64 + n*16 + l15;
                int cb  = col * 2;
                float w4s = W4[col], w4p = W4[DD + col], bias = b3v[col];
                { float z = acc0[m][n][r] + bias;
                  float e = __expf(-20.f * fabsf(z));
                  float d2 = 1.f + e;
                  float rd = __builtin_amdgcn_rcpf(d2);
                  float h4 = fmaxf(z, 0.f) + __logf(d2) * 0.05f;
                  float sg = (z > 0.f ? 1.f : e) * rd;
                  pp0 = fmaf(w4p, h4, pp0);
                  stA(TA0 + 32768, row, cb, w4s * sg); }
                { float z = acc1[m][n][r] + bias;
                  float e = __expf(-20.f * fabsf(z));
                  float d2 = 1.f + e;
                  float rd = __builtin_amdgcn_rcpf(d2);
                  float h4 = fmaxf(z, 0.f) + __logf(d2) * 0.05f;
                  float sg = (z > 0.f ? 1.f : e) * rd;
                  pp1 = fmaf(w4p, h4, pp1);
                  stA(TA1 + 32768, row, cb, w4s * sg); }
            }
            pp0 += __shfl_xor(pp0, 1); pp0 += __shfl_xor(pp0, 2);
            pp0 += __shfl_xor(pp0, 4); pp0 += __shfl_xor(pp0, 8);
            pp1 += __shfl_xor(pp1, 1); pp1 += __shfl_xor(pp1, 2);
            pp1 += __shfl_xor(pp1, 4); pp1 += __shfl_xor(pp1, 8);
            if (l15 == 0) { pbuf[0][wv][row] = pp0; pbuf[1][wv][row] = pp1; }
        }
    __syncthreads();

    // ---- bwd0: gz3 = (gz4 W3^T) * sigma3 (sigma3 via ldh of h3 @ slot0) -> slot0
    ZACC(acc0) ZACC(acc1)
    if constexpr (PREP) { KLOOP_P(5, 1) } else { KLOOP_BW(W3, 1) }
    #pragma unroll
    for (int n = 0; n < 4; ++n) {
        int cb = (wv*64 + n*16 + l15) * 2;
        #pragma unroll
        for (int m = 0; m < 2; ++m)
            #pragma unroll
            for (int r = 0; r < 4; ++r) {
                int row = m*16 + g16*4 + r;
                { float h3 = ldh(TA0, row, cb);
                  float sg = 1.f - __expf(-20.f * h3);
                  stA(TA0, row, cb, sg * acc0[m][n][r]); }
                { float h3 = ldh(TA1, row, cb);
                  float sg = 1.f - __expf(-20.f * h3);
                  stA(TA1, row, cb, sg * acc1[m][n][r]); }
            }
    }
    __syncthreads();

    // ---- bwd1: gz2 = (gz3 W2^T) * sigma2 (regs) -> slot1
    ZACC(acc0) ZACC(acc1)
    if constexpr (PREP) { KLOOP_P(4, 0) } else { KLOOP_BW(W2, 0) }
    #pragma unroll
    for (int n = 0; n < 4; ++n) {
        int cb = (wv*64 + n*16 + l15) * 2;
        #pragma unroll
        for (int m = 0; m < 2; ++m)
            #pragma unroll
            for (int r = 0; r < 4; ++r) {
                int row = m*16 + g16*4 + r;
                int idx = m*16 + n*4 + r;
                stA(TA0 + 32768, row, cb, (float)sg2a[idx>>3][idx&7] * acc0[m][n][r]);
                stA(TA1 + 32768, row, cb, (float)sg2b[idx>>3][idx&7] * acc1[m][n][r]);
            }
    }
    __syncthreads();

    // ---- bwd2: gz1 = (gz2 W1^T) * sigma1 (recomputed from x, W0) -> slot0
    ZACC(acc0) ZACC(acc1)
    if constexpr (PREP) { KLOOP_P(3, 1) } else { KLOOP_BW(W1, 1) }
    #pragma unroll
    for (int n = 0; n < 4; ++n) {
        int col = wv*64 + n*16 + l15;
        int cb  = col * 2;
        float w00 = W0[col*3], w01 = W0[col*3+1], w02 = W0[col*3+2], bb = b0v[col];
        #pragma unroll
        for (int m = 0; m < 2; ++m)
            #pragma unroll
            for (int r = 0; r < 4; ++r) {
                int row = m*16 + g16*4 + r;
                { float z = fmaf(w00, txb[row*3], fmaf(w01, txb[row*3+1], fmaf(w02, txb[row*3+2], bb)));
                  float e = __expf(-20.f * fabsf(z));
                  float sg = (z > 0.f ? 1.f : e) * __builtin_amdgcn_rcpf(1.f + e);
                  stA(TA0, row, cb, sg * acc0[m][n][r]); }
                { int s = 32 + row;
                  float z = fmaf(w00, txb[s*3], fmaf(w01, txb[s*3+1], fmaf(w02, txb[s*3+2], bb)));
                  float e = __expf(-20.f * fabsf(z));
                  float sg = (z > 0.f ? 1.f : e) * __builtin_amdgcn_rcpf(1.f + e);
                  stA(TA1, row, cb, sg * acc1[m][n][r]); }
            }
    }
    __syncthreads();

    // ---- final: u = (dy, -dx) from gz1 . W0 cols; p from pbuf
    {
        const int kb = lane * 8;
        float wyr[8], wxr[8];
        #pragma unroll
        for (int j = 0; j < 8; ++j) {
            wyr[j] = W0[(kb + j) * 3 + 2];
            wxr[j] = W0[(kb + j) * 3 + 1];
        }
        float bp = b4v[1];
        #pragma unroll
        for (int ii = 0; ii < 8; ++ii) {
            int s   = wv * 8 + ii;
            int row = s & 31;
            const char* Gt = ab + (s >> 5) * 65536;  // slot0 of the tile
            f16x8 gg = ldA8(Gt, row, lane * 16);
            float dy = 0.f, dx = 0.f;
            #pragma unroll
            for (int j = 0; j < 8; ++j) {
                dy = fmaf(wyr[j], (float)gg[j], dy);
                dx = fmaf(wxr[j], (float)gg[j], dx);
            }
            #pragma unroll
            for (int mk = 1; mk < 64; mk <<= 1) {
                dy += __shfl_xor(dy, mk);
                dx += __shfl_xor(dx, mk);
            }
            if (lane == 0) {
                float ps = bp;
                #pragma unroll
                for (int w = 0; w < 8; ++w) ps += pbuf[s >> 5][w][row];
                float* o = out + (s0g + s) * 3;
                o[0] = dy;        // ds/dy
                o[1] = -dx;       // -ds/dx
                o[2] = ps;        // pressure
            }
        }
    }
}

extern "C" void kernel_launch(void* const* d_in, const int* in_sizes, int n_in,
                              void* d_out, int out_size, void* d_ws, size_t ws_size,
                              hipStream_t stream) {
    const float* tx = (const float*)d_in[0];
    const float* W0 = (const float*)d_in[1]; const float* b0 = (const float*)d_in[2];
    const float* W1 = (const float*)d_in[3]; const float* b1 = (const float*)d_in[4];
    const float* W2 = (const float*)d_in[5]; const float* b2 = (const float*)d_in[6];
    const float* W3 = (const float*)d_in[7]; const float* b3 = (const float*)d_in[8];
    const float* W4 = (const float*)d_in[9]; const float* b4 = (const float*)d_in[10];
    float* out = (float*)d_out;

    const size_t need = (size_t)6 * 512 * 512 * sizeof(f16);  // 3 MB packs
    if (ws_size >= need) {
        f16* wp = (f16*)d_ws;
        prep_w<<<(6 * 16 * 32 * 64 + 255) / 256, 256, 0, stream>>>(W1, W2, W3, wp);
        mlp_fused<true><<<NBLK, 512, 0, stream>>>(tx, W0, b0, W1, b1, W2, b2, W3, b3, W4, b4, wp, out);
    } else {
        mlp_fused<false><<<NBLK, 512, 0, stream>>>(tx, W0, b0, W1, b1, W2, b2, W3, b3, W4, b4, nullptr, out);
    }
}